// Round 21
// baseline (64.109 us; speedup 1.0000x reference)
//
#include <hip/hip_runtime.h>

#define B_   64
#define C_   12
#define NC_  16
#define N0_  2048
#define N1_  1000
#define N2_  500
#define N3_  100
#define AGENT __HIP_MEMORY_SCOPE_AGENT

__device__ __forceinline__ float wred(float v) {
#pragma unroll
    for (int off = 32; off > 0; off >>= 1) v += __shfl_xor(v, off, 64);
    return v;
}

// ===== K1: h1 = relu(x·W1b^T + b1b). grid (250,12)×256, 1 row/wave (32 weight VGPRs). =====
// Occupancy probe: half the register footprint of the 2-row champion, 2x the waves.
// Block (0,0) zeroes the 2048-int y1acc/cnt region.
__global__ __launch_bounds__(256)
void k_l1b(const float* __restrict__ x, const int* __restrict__ cls,
           const float* __restrict__ W1b, const float* __restrict__ b1b,
           float* __restrict__ h1, int* __restrict__ zctrl) {
    if (blockIdx.x == 0 && blockIdx.y == 0) {
        for (int i = threadIdx.x; i < 2048; i += 256) zctrl[i] = 0;
    }
    const int c    = blockIdx.y;
    const int lane = threadIdx.x & 63;
    const int wave = threadIdx.x >> 6;
    const unsigned long long m = __ballot(cls[lane] == c);
    if (m == 0ull) return;

    const int j = blockIdx.x * 4 + wave;                      // 0..999
    const float4* wr = (const float4*)(W1b + ((size_t)c * N1_ + j) * N0_);
    float4 w[8];
#pragma unroll
    for (int f = 0; f < 8; ++f) w[f] = wr[f * 64 + lane];
    const float bias = b1b[c * N1_ + j];

    for (unsigned long long mm = m; mm; mm &= (mm - 1ull)) {
        const int b = (int)__builtin_ctzll(mm);
        const float4* xr = (const float4*)(x + (size_t)b * N0_);
        float a = 0.f;
#pragma unroll
        for (int f = 0; f < 8; ++f) {
            const float4 xv = xr[f * 64 + lane];
            a += w[f].x * xv.x + w[f].y * xv.y + w[f].z * xv.z + w[f].w * xv.w;
        }
        const float s = wred(a);
        if (lane == 0)
            h1[(size_t)b * N1_ + j] = fmaxf(s + bias, 0.f);
    }
}

// ===== K2: 256 blocks × 1024 thr, block (b=blk>>2, q=blk&3). Wait-free last-arrival merge. =====
// (Round-20 champion, byte-identical.)
__global__ __launch_bounds__(1024)
void k_perb2(const float* __restrict__ x, const int* __restrict__ cls,
             const float* __restrict__ h1,
             const float* __restrict__ W2b, const float* __restrict__ b2b,
             const float* __restrict__ W3b, const float* __restrict__ b3b,
             const float* __restrict__ W1r, const float* __restrict__ b1r,
             const float* __restrict__ W2r, const float* __restrict__ b2r,
             float* __restrict__ y1acc, int* __restrict__ cnt,
             float* __restrict__ out_y1, float* __restrict__ out_y2) {
    const int b    = blockIdx.x >> 2;
    const int q    = blockIdx.x & 3;
    const int tid  = threadIdx.x;
    const int lane = tid & 63;
    const int wave = tid >> 6;                     // 0..15
    const int c    = cls[b];

    __shared__ __align__(16) float s_h1[N1_];      // 4 KB
    __shared__ float s_w3[NC_][125];               // 8 KB (stride 125 odd -> conflict-free)
    __shared__ float s_part[16][NC_];              // 1 KB
    __shared__ __align__(16) float s_x[N0_];       // 8 KB
    __shared__ float s_r[N3_];
    __shared__ int   s_old;
    __shared__ int   s_e;

    if (tid < 250) ((float4*)s_h1)[tid] = ((const float4*)(h1 + (size_t)b * N1_))[tid];
    else if (tid >= 512) {                         // prefetch x[b] overlapped with quarter phase
        const int i = tid - 512;                   // 512 threads -> 512 float4
        ((float4*)s_x)[i] = ((const float4*)(x + (size_t)b * N0_))[i];
    }
    for (int i = tid; i < NC_ * 125; i += 1024) {  // W3b[c][mi][4*idx+q]
        const int mi = i / 125, idx = i - mi * 125;
        s_w3[mi][idx] = W3b[((size_t)c * NC_ + mi) * N2_ + 4 * idx + q];
    }
    __syncthreads();

    // ---- quarter phase: rows j = 4*idx+q, y1 partials in lane<16 regs ----
    float accm = 0.f;
    for (int idx = wave; idx < 125; idx += 16) {
        const int j = 4 * idx + q;
        const float4* wr = (const float4*)(W2b + ((size_t)c * N2_ + j) * N1_);
        const float4* xr = (const float4*)s_h1;
        float a = 0.f;
#pragma unroll
        for (int f = 0; f < 4; ++f) {
            const int id4 = f * 64 + lane;
            if (id4 < N1_ / 4) {
                const float4 wv = wr[id4], xv = xr[id4];
                a += wv.x * xv.x + wv.y * xv.y + wv.z * xv.z + wv.w * xv.w;
            }
        }
        const float h2v = fmaxf(wred(a) + b2b[c * N2_ + j], 0.f);   // all lanes
        if (lane < NC_) accm += h2v * s_w3[lane][idx];
    }
    if (lane < NC_) s_part[wave][lane] = accm;
    __syncthreads();

    // ---- wait-free merge: 16 relaxed adds + 1 ACQ_REL counter; non-last blocks exit ----
    if (wave == 0 && lane < NC_) {
        float t = 0.f;
#pragma unroll
        for (int w = 0; w < 16; ++w) t += s_part[w][lane];
        __hip_atomic_fetch_add(&y1acc[b * NC_ + lane], t, __ATOMIC_RELAXED, AGENT);
    }
    if (tid == 0) {
        __threadfence();
        s_old = __hip_atomic_fetch_add(&cnt[b * 16], 1, __ATOMIC_ACQ_REL, AGENT);
    }
    __syncthreads();
    if (s_old != 3) return;                        // only the 4th arrival continues

    // ---- finalizer: y1 + argmax, then full r-path + y2 (s_x already staged) ----
    if (wave == 0) {
        float v  = -1e30f;
        int   mi = lane;
        if (lane < NC_) {
            v = y1acc[b * NC_ + lane] + b3b[c * NC_ + lane];
            out_y1[b * NC_ + lane] = v;
        }
#pragma unroll
        for (int off = 8; off > 0; off >>= 1) {    // first-occurrence argmax over 16
            const float ov = __shfl_xor(v,  off, 16);
            const int   om = __shfl_xor(mi, off, 16);
            if (ov > v || (ov == v && om < mi)) { v = ov; mi = om; }
        }
        if (lane == 0) s_e = c * NC_ + mi;
    }
    __syncthreads();
    const int e = s_e;

    {   // r[b][j] = relu(x·W1r[e][j] + b1r), 100 rows, 2/wave/iter
        const float4* xr = (const float4*)s_x;     // 512 float4
        for (int j0 = wave * 2; j0 < N3_; j0 += 32) {
            const float4* wr0 = (const float4*)(W1r + ((size_t)e * N3_ + j0) * N0_);
            const float4* wr1 = wr0 + (N0_ / 4);
            float a0 = 0.f, a1 = 0.f;
#pragma unroll
            for (int f = 0; f < 8; ++f) {
                const int idx = f * 64 + lane;
                const float4 xv = xr[idx];
                const float4 w0 = wr0[idx], w1 = wr1[idx];
                a0 += w0.x * xv.x + w0.y * xv.y + w0.z * xv.z + w0.w * xv.w;
                a1 += w1.x * xv.x + w1.y * xv.y + w1.z * xv.z + w1.w * xv.w;
            }
            const float s0 = wred(a0), s1 = wred(a1);
            if (lane == 0) {
                s_r[j0]     = fmaxf(s0 + b1r[e * N3_ + j0],     0.f);
                s_r[j0 + 1] = fmaxf(s1 + b1r[e * N3_ + j0 + 1], 0.f);
            }
        }
    }
    __syncthreads();

    if (wave < 3) {                                // y2
        const float* w2 = W2r + ((size_t)e * 3 + wave) * N3_;
        float a = s_r[lane] * w2[lane];
        if (lane < N3_ - 64) a += s_r[64 + lane] * w2[64 + lane];
        const float s = wred(a);
        if (lane == 0) out_y2[b * 3 + wave] = s + b2r[e * 3 + wave];
    }
}

extern "C" void kernel_launch(void* const* d_in, const int* in_sizes, int n_in,
                              void* d_out, int out_size, void* d_ws, size_t ws_size,
                              hipStream_t stream) {
    const float* x   = (const float*)d_in[0];
    const int*   cls = (const int*)  d_in[1];
    const float* W1b = (const float*)d_in[2];
    const float* b1b = (const float*)d_in[3];
    const float* W2b = (const float*)d_in[4];
    const float* b2b = (const float*)d_in[5];
    const float* W3b = (const float*)d_in[6];
    const float* b3b = (const float*)d_in[7];
    const float* W1r = (const float*)d_in[8];
    const float* b1r = (const float*)d_in[9];
    const float* W2r = (const float*)d_in[10];
    const float* b2r = (const float*)d_in[11];

    float* out_y1 = (float*)d_out;                 // [0, 1024)
    float* out_y2 = (float*)d_out + B_ * NC_;      // [1024, 1216)

    char*  ws    = (char*)d_ws;
    float* h1    = (float*)(ws);                   // 256000 B
    float* y1acc = (float*)(ws + 256000);          // 64*16 floats = 4096 B  (zeroed by K1)
    int*   cnt   = (int*)  (ws + 260096);          // 64*16 ints   = 4096 B  (zeroed by K1)
    int*   zctrl = (int*)  (ws + 256000);          // 2048 ints

    hipLaunchKernelGGL(k_l1b, dim3(250, 12), dim3(256), 0, stream,
                       x, cls, W1b, b1b, h1, zctrl);
    hipLaunchKernelGGL(k_perb2, dim3(256), dim3(1024), 0, stream,
                       x, cls, h1, W2b, b2b, W3b, b3b, W1r, b1r, W2r, b2r,
                       y1acc, cnt, out_y1, out_y2);
}

// Round 22
// 59.178 us; speedup vs baseline: 1.0833x; 1.0833x over previous
//
#include <hip/hip_runtime.h>

#define B_   64
#define C_   12
#define NC_  16
#define N0_  2048
#define N1_  1000
#define N2_  500
#define N3_  100
#define AGENT __HIP_MEMORY_SCOPE_AGENT

__device__ __forceinline__ float wred(float v) {
#pragma unroll
    for (int off = 32; off > 0; off >>= 1) v += __shfl_xor(v, off, 64);
    return v;
}

// ===== K1: h1 = relu(x·W1b^T + b1b). grid (125,12)×256, 2 rows/wave (proven optimum). =====
// Block (0,0) zeroes the 2048-int y1acc/cnt region.
__global__ __launch_bounds__(256)
void k_l1b(const float* __restrict__ x, const int* __restrict__ cls,
           const float* __restrict__ W1b, const float* __restrict__ b1b,
           float* __restrict__ h1, int* __restrict__ zctrl) {
    if (blockIdx.x == 0 && blockIdx.y == 0) {
        for (int i = threadIdx.x; i < 2048; i += 256) zctrl[i] = 0;
    }
    const int c    = blockIdx.y;
    const int lane = threadIdx.x & 63;
    const int wave = threadIdx.x >> 6;
    const unsigned long long m = __ballot(cls[lane] == c);
    if (m == 0ull) return;

    const int j0 = blockIdx.x * 8 + wave * 2;                 // < 1000 always
    const float4* wr0 = (const float4*)(W1b + ((size_t)c * N1_ + j0) * N0_);
    const float4* wr1 = wr0 + (N0_ / 4);
    float4 w0[8], w1[8];
#pragma unroll
    for (int f = 0; f < 8; ++f) { w0[f] = wr0[f * 64 + lane]; w1[f] = wr1[f * 64 + lane]; }
    const float bias0 = b1b[c * N1_ + j0];
    const float bias1 = b1b[c * N1_ + j0 + 1];

    for (unsigned long long mm = m; mm; mm &= (mm - 1ull)) {
        const int b = (int)__builtin_ctzll(mm);
        const float4* xr = (const float4*)(x + (size_t)b * N0_);
        float a0 = 0.f, a1 = 0.f;
#pragma unroll
        for (int f = 0; f < 8; ++f) {
            const float4 xv = xr[f * 64 + lane];
            a0 += w0[f].x * xv.x + w0[f].y * xv.y + w0[f].z * xv.z + w0[f].w * xv.w;
            a1 += w1[f].x * xv.x + w1[f].y * xv.y + w1[f].z * xv.z + w1[f].w * xv.w;
        }
        const float s0 = wred(a0), s1 = wred(a1);
        if (lane == 0) {
            h1[(size_t)b * N1_ + j0]     = fmaxf(s0 + bias0, 0.f);
            h1[(size_t)b * N1_ + j0 + 1] = fmaxf(s1 + bias1, 0.f);
        }
    }
}

// ===== K2: 256 blocks × 1024 thr, block (b=blk>>2, q=blk&3). Wait-free last-arrival merge. =====
// Quarter phase folds h2 rows j=4*idx+q directly into 16 y1-partials (h2 never hits memory).
// Merge: 16 relaxed atomicAdds + 1 ACQ_REL counter; 4th arrival finalizes. x prefetched.
__global__ __launch_bounds__(1024)
void k_perb2(const float* __restrict__ x, const int* __restrict__ cls,
             const float* __restrict__ h1,
             const float* __restrict__ W2b, const float* __restrict__ b2b,
             const float* __restrict__ W3b, const float* __restrict__ b3b,
             const float* __restrict__ W1r, const float* __restrict__ b1r,
             const float* __restrict__ W2r, const float* __restrict__ b2r,
             float* __restrict__ y1acc, int* __restrict__ cnt,
             float* __restrict__ out_y1, float* __restrict__ out_y2) {
    const int b    = blockIdx.x >> 2;
    const int q    = blockIdx.x & 3;
    const int tid  = threadIdx.x;
    const int lane = tid & 63;
    const int wave = tid >> 6;                     // 0..15
    const int c    = cls[b];

    __shared__ __align__(16) float s_h1[N1_];      // 4 KB
    __shared__ float s_w3[NC_][125];               // 8 KB (stride 125 odd -> conflict-free)
    __shared__ float s_part[16][NC_];              // 1 KB
    __shared__ __align__(16) float s_x[N0_];       // 8 KB
    __shared__ float s_r[N3_];
    __shared__ int   s_old;
    __shared__ int   s_e;

    if (tid < 250) ((float4*)s_h1)[tid] = ((const float4*)(h1 + (size_t)b * N1_))[tid];
    else if (tid >= 512) {                         // prefetch x[b] overlapped with quarter phase
        const int i = tid - 512;                   // 512 threads -> 512 float4
        ((float4*)s_x)[i] = ((const float4*)(x + (size_t)b * N0_))[i];
    }
    for (int i = tid; i < NC_ * 125; i += 1024) {  // W3b[c][mi][4*idx+q]
        const int mi = i / 125, idx = i - mi * 125;
        s_w3[mi][idx] = W3b[((size_t)c * NC_ + mi) * N2_ + 4 * idx + q];
    }
    __syncthreads();

    // ---- quarter phase: rows j = 4*idx+q, y1 partials in lane<16 regs ----
    float accm = 0.f;
    for (int idx = wave; idx < 125; idx += 16) {
        const int j = 4 * idx + q;
        const float4* wr = (const float4*)(W2b + ((size_t)c * N2_ + j) * N1_);
        const float4* xr = (const float4*)s_h1;
        float a = 0.f;
#pragma unroll
        for (int f = 0; f < 4; ++f) {
            const int id4 = f * 64 + lane;
            if (id4 < N1_ / 4) {
                const float4 wv = wr[id4], xv = xr[id4];
                a += wv.x * xv.x + wv.y * xv.y + wv.z * xv.z + wv.w * xv.w;
            }
        }
        const float h2v = fmaxf(wred(a) + b2b[c * N2_ + j], 0.f);   // all lanes
        if (lane < NC_) accm += h2v * s_w3[lane][idx];
    }
    if (lane < NC_) s_part[wave][lane] = accm;
    __syncthreads();

    // ---- wait-free merge: 16 relaxed adds + 1 ACQ_REL counter; non-last blocks exit ----
    if (wave == 0 && lane < NC_) {
        float t = 0.f;
#pragma unroll
        for (int w = 0; w < 16; ++w) t += s_part[w][lane];
        __hip_atomic_fetch_add(&y1acc[b * NC_ + lane], t, __ATOMIC_RELAXED, AGENT);
    }
    if (tid == 0) {
        __threadfence();
        s_old = __hip_atomic_fetch_add(&cnt[b * 16], 1, __ATOMIC_ACQ_REL, AGENT);
    }
    __syncthreads();
    if (s_old != 3) return;                        // only the 4th arrival continues

    // ---- finalizer: y1 + argmax, then full r-path + y2 (s_x already staged) ----
    if (wave == 0) {
        float v  = -1e30f;
        int   mi = lane;
        if (lane < NC_) {
            v = y1acc[b * NC_ + lane] + b3b[c * NC_ + lane];
            out_y1[b * NC_ + lane] = v;
        }
#pragma unroll
        for (int off = 8; off > 0; off >>= 1) {    // first-occurrence argmax over 16
            const float ov = __shfl_xor(v,  off, 16);
            const int   om = __shfl_xor(mi, off, 16);
            if (ov > v || (ov == v && om < mi)) { v = ov; mi = om; }
        }
        if (lane == 0) s_e = c * NC_ + mi;
    }
    __syncthreads();
    const int e = s_e;

    {   // r[b][j] = relu(x·W1r[e][j] + b1r), 100 rows, 2/wave/iter
        const float4* xr = (const float4*)s_x;     // 512 float4
        for (int j0 = wave * 2; j0 < N3_; j0 += 32) {
            const float4* wr0 = (const float4*)(W1r + ((size_t)e * N3_ + j0) * N0_);
            const float4* wr1 = wr0 + (N0_ / 4);
            float a0 = 0.f, a1 = 0.f;
#pragma unroll
            for (int f = 0; f < 8; ++f) {
                const int idx = f * 64 + lane;
                const float4 xv = xr[idx];
                const float4 w0 = wr0[idx], w1 = wr1[idx];
                a0 += w0.x * xv.x + w0.y * xv.y + w0.z * xv.z + w0.w * xv.w;
                a1 += w1.x * xv.x + w1.y * xv.y + w1.z * xv.z + w1.w * xv.w;
            }
            const float s0 = wred(a0), s1 = wred(a1);
            if (lane == 0) {
                s_r[j0]     = fmaxf(s0 + b1r[e * N3_ + j0],     0.f);
                s_r[j0 + 1] = fmaxf(s1 + b1r[e * N3_ + j0 + 1], 0.f);
            }
        }
    }
    __syncthreads();

    if (wave < 3) {                                // y2
        const float* w2 = W2r + ((size_t)e * 3 + wave) * N3_;
        float a = s_r[lane] * w2[lane];
        if (lane < N3_ - 64) a += s_r[64 + lane] * w2[64 + lane];
        const float s = wred(a);
        if (lane == 0) out_y2[b * 3 + wave] = s + b2r[e * 3 + wave];
    }
}

extern "C" void kernel_launch(void* const* d_in, const int* in_sizes, int n_in,
                              void* d_out, int out_size, void* d_ws, size_t ws_size,
                              hipStream_t stream) {
    const float* x   = (const float*)d_in[0];
    const int*   cls = (const int*)  d_in[1];
    const float* W1b = (const float*)d_in[2];
    const float* b1b = (const float*)d_in[3];
    const float* W2b = (const float*)d_in[4];
    const float* b2b = (const float*)d_in[5];
    const float* W3b = (const float*)d_in[6];
    const float* b3b = (const float*)d_in[7];
    const float* W1r = (const float*)d_in[8];
    const float* b1r = (const float*)d_in[9];
    const float* W2r = (const float*)d_in[10];
    const float* b2r = (const float*)d_in[11];

    float* out_y1 = (float*)d_out;                 // [0, 1024)
    float* out_y2 = (float*)d_out + B_ * NC_;      // [1024, 1216)

    char*  ws    = (char*)d_ws;
    float* h1    = (float*)(ws);                   // 256000 B
    float* y1acc = (float*)(ws + 256000);          // 64*16 floats = 4096 B  (zeroed by K1)
    int*   cnt   = (int*)  (ws + 260096);          // 64*16 ints   = 4096 B  (zeroed by K1)
    int*   zctrl = (int*)  (ws + 256000);          // 2048 ints

    hipLaunchKernelGGL(k_l1b, dim3(125, 12), dim3(256), 0, stream,
                       x, cls, W1b, b1b, h1, zctrl);
    hipLaunchKernelGGL(k_perb2, dim3(256), dim3(1024), 0, stream,
                       x, cls, h1, W2b, b2b, W3b, b3b, W1r, b1r, W2r, b2r,
                       y1acc, cnt, out_y1, out_y2);
}